// Round 1
// baseline (117.272 us; speedup 1.0000x reference)
//
#include <hip/hip_runtime.h>
#include <math.h>

// Problem constants (from reference)
#define BB    16      // batch
#define HH    112     // H == W
#define OO    256     // output channels
#define KK    5       // kernel size
#define OHW   108     // output H == W (112 - 5 + 1)
#define PIX   4       // output pixels per thread (horizontally adjacent)
#define OWG   27      // 108 / 4 groups per output row
#define OCHUNK 64     // o-channels per block (grid.y = 256/64 = 4)

// Each thread: owns 4 adjacent output pixels (one row, ow0..ow0+3) for all 64
// o's of its chunk. Windows (5x8 per image) live in registers; weights are
// broadcast from LDS (float4 reads, zero-padded to 28 floats per filter).
__global__ __launch_bounds__(256, 2)
void dist_rbf_kernel(const float* __restrict__ gx, const float* __restrict__ rx,
                     const float* __restrict__ gw, const float* __restrict__ rw,
                     const float* __restrict__ stdp, float* __restrict__ out)
{
    __shared__ float lwg[OCHUNK * 28];
    __shared__ float lwr[OCHUNK * 28];
    __shared__ float lw2g[OCHUNK];
    __shared__ float lw2r[OCHUNK];

    const int tid   = threadIdx.x;
    const int obase = blockIdx.y * OCHUNK;

    // ---- stage weights into LDS, zero-padded 25 -> 28 floats per filter ----
    for (int idx = tid; idx < OCHUNK * 28; idx += 256) {
        int o = idx / 28;
        int i = idx - o * 28;
        float vg = 0.f, vr = 0.f;
        if (i < 25) {
            vg = gw[(obase + o) * 25 + i];
            vr = rw[(obase + o) * 25 + i];
        }
        lwg[idx] = vg;
        lwr[idx] = vr;
    }
    // per-filter ||w||^2
    if (tid < OCHUNK) {
        float s = 0.f;
        #pragma unroll
        for (int i = 0; i < 25; i++) { float v = gw[(obase + tid) * 25 + i]; s = fmaf(v, v, s); }
        lw2g[tid] = s;
    } else if (tid < 2 * OCHUNK) {
        int o = tid - OCHUNK;
        float s = 0.f;
        #pragma unroll
        for (int i = 0; i < 25; i++) { float v = rw[(obase + o) * 25 + i]; s = fmaf(v, v, s); }
        lw2r[o] = s;
    }
    __syncthreads();

    const int g = blockIdx.x * 256 + tid;
    if (g >= BB * OHW * OWG) return;   // no barriers after this point

    const int b   = g / (OHW * OWG);
    const int rem = g - b * (OHW * OWG);
    const int oh  = rem / OWG;
    const int ow0 = (rem - oh * OWG) * PIX;

    const float s   = stdp[0];
    const float kneg = -1.f / (2.f * s * s);

    // ---- load 5x8 windows for both images into registers ----
    float wing[5][8], winr[5][8];
    const float* gbase = gx + ((b * HH) + oh) * HH + ow0;  // [B,1,112,112]
    const float* rbase = rx + ((b * HH) + oh) * HH + ow0;
    #pragma unroll
    for (int r = 0; r < 5; r++) {
        float4 a0 = *(const float4*)(gbase + r * HH);
        float4 a1 = *(const float4*)(gbase + r * HH + 4);
        wing[r][0] = a0.x; wing[r][1] = a0.y; wing[r][2] = a0.z; wing[r][3] = a0.w;
        wing[r][4] = a1.x; wing[r][5] = a1.y; wing[r][6] = a1.z; wing[r][7] = a1.w;
        float4 b0 = *(const float4*)(rbase + r * HH);
        float4 b1 = *(const float4*)(rbase + r * HH + 4);
        winr[r][0] = b0.x; winr[r][1] = b0.y; winr[r][2] = b0.z; winr[r][3] = b0.w;
        winr[r][4] = b1.x; winr[r][5] = b1.y; winr[r][6] = b1.z; winr[r][7] = b1.w;
    }

    // ---- per-pixel sum of squares of the window (x2 term) ----
    float x2g[PIX], x2r[PIX];
    #pragma unroll
    for (int px = 0; px < PIX; px++) {
        float sg = 0.f, sr = 0.f;
        #pragma unroll
        for (int r = 0; r < 5; r++)
            #pragma unroll
            for (int c = 0; c < 5; c++) {
                sg = fmaf(wing[r][px + c], wing[r][px + c], sg);
                sr = fmaf(winr[r][px + c], winr[r][px + c], sr);
            }
        x2g[px] = sg;
        x2r[px] = sr;
    }

    float* outp = out + (((size_t)(b * OO + obase) * OHW) + oh) * OHW + ow0;

    // ---- main loop over the 64 o's of this chunk ----
    for (int o = 0; o < OCHUNK; o++) {
        // weights: 7 float4 broadcasts each (zero-padded, 16B aligned)
        float wgf[28], wrf[28];
        const float4* wg4 = (const float4*)(lwg + o * 28);
        const float4* wr4 = (const float4*)(lwr + o * 28);
        #pragma unroll
        for (int i = 0; i < 7; i++) {
            ((float4*)wgf)[i] = wg4[i];
            ((float4*)wrf)[i] = wr4[i];
        }

        float acg[PIX] = {0.f, 0.f, 0.f, 0.f};
        float acr[PIX] = {0.f, 0.f, 0.f, 0.f};
        #pragma unroll
        for (int r = 0; r < 5; r++)
            #pragma unroll
            for (int c = 0; c < 5; c++) {
                const float wgv = wgf[r * 5 + c];
                const float wrv = wrf[r * 5 + c];
                #pragma unroll
                for (int px = 0; px < PIX; px++) {
                    acg[px] = fmaf(wing[r][px + c], wgv, acg[px]);
                    acr[px] = fmaf(winr[r][px + c], wrv, acr[px]);
                }
            }

        const float w2gv = lw2g[o];
        const float w2rv = lw2r[o];
        float4 res;
        float* rp = (float*)&res;
        #pragma unroll
        for (int px = 0; px < PIX; px++) {
            float d2g = fmaf(-2.f, acg[px], x2g[px] + w2gv);
            float d2r = fmaf(-2.f, acr[px], x2r[px] + w2rv);
            d2g = fmaxf(d2g, 1e-12f);
            d2r = fmaxf(d2r, 1e-12f);
            float d = sqrtf(d2g) + sqrtf(d2r);
            rp[px] = __expf(kneg * d * d);
        }
        *(float4*)(outp + (size_t)o * (OHW * OHW)) = res;
    }
}

extern "C" void kernel_launch(void* const* d_in, const int* in_sizes, int n_in,
                              void* d_out, int out_size, void* d_ws, size_t ws_size,
                              hipStream_t stream) {
    const float* gx   = (const float*)d_in[0];
    const float* rx   = (const float*)d_in[1];
    const float* gw   = (const float*)d_in[2];
    const float* rw   = (const float*)d_in[3];
    const float* stdp = (const float*)d_in[4];
    float* out = (float*)d_out;

    const int ngroups = BB * OHW * OWG;               // 46656 threads of work
    dim3 grid((ngroups + 255) / 256, OO / OCHUNK, 1); // 183 x 4
    dim3 block(256, 1, 1);
    dist_rbf_kernel<<<grid, block, 0, stream>>>(gx, rx, gw, rw, stdp, out);
}

// Round 3
// 105.669 us; speedup vs baseline: 1.1098x; 1.1098x over previous
//
#include <hip/hip_runtime.h>
#include <math.h>

// Problem constants (from reference)
#define BB    16      // batch
#define HH    112     // H == W
#define OO    256     // output channels
#define KK    5       // kernel size
#define OHW   108     // output H == W (112 - 5 + 1)
#define PIX   4       // output pixels per thread (horizontally adjacent)
#define OWG   27      // 108 / 4 groups per output row
#define OCHUNK 64     // o-channels per block (grid.y = 256/64 = 4)

// Each thread: 4 adjacent output pixels (one row) for all 64 o's of its chunk.
// Windows (5x8 per image, 80 floats) live in VGPRs; weights are read through
// wave-uniform global loads (-> s_load into SGPRs, SMEM pipe, zero VGPR cost).
// amdgpu_waves_per_eu(1,4) stops the compiler from rematerializing the
// windows to chase 8-waves occupancy (round-1 pathology: VGPR=64, 4x VALU).
__global__ __attribute__((amdgpu_flat_work_group_size(256, 256),
                          amdgpu_waves_per_eu(1, 4)))
void dist_rbf_kernel(const float* __restrict__ gx, const float* __restrict__ rx,
                     const float* __restrict__ gw, const float* __restrict__ rw,
                     const float* __restrict__ stdp, float* __restrict__ out)
{
    __shared__ float lw2g[OCHUNK];
    __shared__ float lw2r[OCHUNK];

    const int tid   = threadIdx.x;
    const int obase = blockIdx.y * OCHUNK;

    // per-filter ||w||^2 into LDS (once per block)
    if (tid < OCHUNK) {
        float s = 0.f;
        #pragma unroll
        for (int i = 0; i < 25; i++) { float v = gw[(obase + tid) * 25 + i]; s = fmaf(v, v, s); }
        lw2g[tid] = s;
    } else if (tid < 2 * OCHUNK) {
        int o = tid - OCHUNK;
        float s = 0.f;
        #pragma unroll
        for (int i = 0; i < 25; i++) { float v = rw[(obase + o) * 25 + i]; s = fmaf(v, v, s); }
        lw2r[o] = s;
    }
    __syncthreads();

    const int g = blockIdx.x * 256 + tid;
    if (g >= BB * OHW * OWG) return;   // no barriers after this point

    const int b   = g / (OHW * OWG);
    const int rem = g - b * (OHW * OWG);
    const int oh  = rem / OWG;
    const int ow0 = (rem - oh * OWG) * PIX;

    const float s    = stdp[0];
    const float kneg = -1.f / (2.f * s * s);

    // ---- load 5x8 windows for both images into registers ----
    float wing[5][8], winr[5][8];
    const float* gbase = gx + ((b * HH) + oh) * HH + ow0;  // [B,1,112,112]
    const float* rbase = rx + ((b * HH) + oh) * HH + ow0;
    #pragma unroll
    for (int r = 0; r < 5; r++) {
        float4 a0 = *(const float4*)(gbase + r * HH);
        float4 a1 = *(const float4*)(gbase + r * HH + 4);
        wing[r][0] = a0.x; wing[r][1] = a0.y; wing[r][2] = a0.z; wing[r][3] = a0.w;
        wing[r][4] = a1.x; wing[r][5] = a1.y; wing[r][6] = a1.z; wing[r][7] = a1.w;
        float4 b0 = *(const float4*)(rbase + r * HH);
        float4 b1 = *(const float4*)(rbase + r * HH + 4);
        winr[r][0] = b0.x; winr[r][1] = b0.y; winr[r][2] = b0.z; winr[r][3] = b0.w;
        winr[r][4] = b1.x; winr[r][5] = b1.y; winr[r][6] = b1.z; winr[r][7] = b1.w;
    }

    // ---- per-pixel sum of squares of the window (x2 term) ----
    float x2g[PIX], x2r[PIX];
    #pragma unroll
    for (int px = 0; px < PIX; px++) {
        float sg = 0.f, sr = 0.f;
        #pragma unroll
        for (int r = 0; r < 5; r++)
            #pragma unroll
            for (int c = 0; c < 5; c++) {
                sg = fmaf(wing[r][px + c], wing[r][px + c], sg);
                sr = fmaf(winr[r][px + c], winr[r][px + c], sr);
            }
        x2g[px] = sg;
        x2r[px] = sr;
    }

    float* outp = out + (((size_t)(b * OO + obase) * OHW) + oh) * OHW + ow0;

    // ---- main loop over the 64 o's of this chunk ----
    for (int o = 0; o < OCHUNK; o++) {
        // wave-uniform weight pointers -> scalar (SMEM) loads
        const float* __restrict__ wgp = gw + (size_t)(obase + o) * 25;
        const float* __restrict__ wrp = rw + (size_t)(obase + o) * 25;

        float acg[PIX] = {0.f, 0.f, 0.f, 0.f};
        float acr[PIX] = {0.f, 0.f, 0.f, 0.f};
        #pragma unroll
        for (int r = 0; r < 5; r++)
            #pragma unroll
            for (int c = 0; c < 5; c++) {
                const float wgv = wgp[r * 5 + c];
                const float wrv = wrp[r * 5 + c];
                #pragma unroll
                for (int px = 0; px < PIX; px++) {
                    acg[px] = fmaf(wing[r][px + c], wgv, acg[px]);
                    acr[px] = fmaf(winr[r][px + c], wrv, acr[px]);
                }
            }

        const float w2gv = lw2g[o];
        const float w2rv = lw2r[o];
        float4 res;
        float* rp = (float*)&res;
        #pragma unroll
        for (int px = 0; px < PIX; px++) {
            float d2g = fmaf(-2.f, acg[px], x2g[px] + w2gv);
            float d2r = fmaf(-2.f, acr[px], x2r[px] + w2rv);
            d2g = fmaxf(d2g, 1e-12f);
            d2r = fmaxf(d2r, 1e-12f);
            float d = __builtin_amdgcn_sqrtf(d2g) + __builtin_amdgcn_sqrtf(d2r);
            rp[px] = __expf(kneg * d * d);
        }
        *(float4*)(outp + (size_t)o * (OHW * OHW)) = res;
    }
}

extern "C" void kernel_launch(void* const* d_in, const int* in_sizes, int n_in,
                              void* d_out, int out_size, void* d_ws, size_t ws_size,
                              hipStream_t stream) {
    const float* gx   = (const float*)d_in[0];
    const float* rx   = (const float*)d_in[1];
    const float* gw   = (const float*)d_in[2];
    const float* rw   = (const float*)d_in[3];
    const float* stdp = (const float*)d_in[4];
    float* out = (float*)d_out;

    const int ngroups = BB * OHW * OWG;               // 46656 threads of work
    dim3 grid((ngroups + 255) / 256, OO / OCHUNK, 1); // 183 x 4
    dim3 block(256, 1, 1);
    dist_rbf_kernel<<<grid, block, 0, stream>>>(gx, rx, gw, rw, stdp, out);
}

// Round 5
// 94.571 us; speedup vs baseline: 1.2400x; 1.1173x over previous
//
#include <hip/hip_runtime.h>
#include <math.h>

// Problem constants (from reference)
#define BB    16      // batch
#define HH    112     // H == W
#define OO    256     // output channels
#define KK    5       // kernel size
#define OHW   108     // output H == W (112 - 5 + 1)
#define PIX   4       // output pixels per thread (horizontally adjacent)
#define OWG   27      // 108 / 4 groups per output row
#define OCHUNK 32     // o-channels per block (grid.y = 256/32 = 8)

// Pin a float into a VGPR with an opaque identity asm: the compiler cannot
// rematerialize or re-sink the producer past this, so the value stays
// register-resident across the o-loop. (Round-3 pathology: VGPR=56, windows
// re-loaded inside the loop -> ~2x VALU/issue inflation.)
#define KEEP(x) asm volatile("" : "+v"(x))

__global__ __attribute__((amdgpu_flat_work_group_size(256, 256),
                          amdgpu_waves_per_eu(1, 4)))
void dist_rbf_kernel(const float* __restrict__ gx, const float* __restrict__ rx,
                     const float* __restrict__ gw, const float* __restrict__ rw,
                     const float* __restrict__ stdp, float* __restrict__ out)
{
    __shared__ float lw2g[OCHUNK];
    __shared__ float lw2r[OCHUNK];

    const int tid   = threadIdx.x;
    const int obase = blockIdx.y * OCHUNK;

    // per-filter ||w||^2 into LDS (once per block)
    if (tid < OCHUNK) {
        float s = 0.f;
        #pragma unroll
        for (int i = 0; i < 25; i++) { float v = gw[(obase + tid) * 25 + i]; s = fmaf(v, v, s); }
        lw2g[tid] = s;
    } else if (tid < 2 * OCHUNK) {
        int o = tid - OCHUNK;
        float s = 0.f;
        #pragma unroll
        for (int i = 0; i < 25; i++) { float v = rw[(obase + o) * 25 + i]; s = fmaf(v, v, s); }
        lw2r[o] = s;
    }
    __syncthreads();

    const int g = blockIdx.x * 256 + tid;
    if (g >= BB * OHW * OWG) return;   // no barriers after this point

    const int b   = g / (OHW * OWG);
    const int rem = g - b * (OHW * OWG);
    const int oh  = rem / OWG;
    const int ow0 = (rem - oh * OWG) * PIX;

    const float s    = stdp[0];
    const float kneg = -1.f / (2.f * s * s);

    // ---- load 5x8 windows for both images into registers ----
    float wing[5][8], winr[5][8];
    const float* gbase = gx + ((b * HH) + oh) * HH + ow0;  // [B,1,112,112]
    const float* rbase = rx + ((b * HH) + oh) * HH + ow0;
    #pragma unroll
    for (int r = 0; r < 5; r++) {
        float4 a0 = *(const float4*)(gbase + r * HH);
        float4 a1 = *(const float4*)(gbase + r * HH + 4);
        wing[r][0] = a0.x; wing[r][1] = a0.y; wing[r][2] = a0.z; wing[r][3] = a0.w;
        wing[r][4] = a1.x; wing[r][5] = a1.y; wing[r][6] = a1.z; wing[r][7] = a1.w;
        float4 b0 = *(const float4*)(rbase + r * HH);
        float4 b1 = *(const float4*)(rbase + r * HH + 4);
        winr[r][0] = b0.x; winr[r][1] = b0.y; winr[r][2] = b0.z; winr[r][3] = b0.w;
        winr[r][4] = b1.x; winr[r][5] = b1.y; winr[r][6] = b1.z; winr[r][7] = b1.w;
    }
    // pin the 160 window values into VGPRs (identity asm, executes once)
    #pragma unroll
    for (int r = 0; r < 5; r++)
        #pragma unroll
        for (int c = 0; c < 8; c++) { KEEP(wing[r][c]); KEEP(winr[r][c]); }

    // ---- per-pixel sum of squares of the window (x2 term) ----
    float x2g[PIX], x2r[PIX];
    #pragma unroll
    for (int px = 0; px < PIX; px++) {
        float sg = 0.f, sr = 0.f;
        #pragma unroll
        for (int r = 0; r < 5; r++)
            #pragma unroll
            for (int c = 0; c < 5; c++) {
                sg = fmaf(wing[r][px + c], wing[r][px + c], sg);
                sr = fmaf(winr[r][px + c], winr[r][px + c], sr);
            }
        x2g[px] = sg;
        x2r[px] = sr;
        KEEP(x2g[px]); KEEP(x2r[px]);
    }

    float* outp = out + (((size_t)(b * OO + obase) * OHW) + oh) * OHW + ow0;

    // ---- main loop over the o's of this chunk ----
    for (int o = 0; o < OCHUNK; o++) {
        // wave-uniform weight pointers -> scalar (SMEM) loads
        const float* __restrict__ wgp = gw + (size_t)(obase + o) * 25;
        const float* __restrict__ wrp = rw + (size_t)(obase + o) * 25;

        float acg[PIX] = {0.f, 0.f, 0.f, 0.f};
        float acr[PIX] = {0.f, 0.f, 0.f, 0.f};
        #pragma unroll
        for (int r = 0; r < 5; r++)
            #pragma unroll
            for (int c = 0; c < 5; c++) {
                const float wgv = wgp[r * 5 + c];
                const float wrv = wrp[r * 5 + c];
                #pragma unroll
                for (int px = 0; px < PIX; px++) {
                    acg[px] = fmaf(wing[r][px + c], wgv, acg[px]);
                    acr[px] = fmaf(winr[r][px + c], wrv, acr[px]);
                }
            }

        const float w2gv = lw2g[o];
        const float w2rv = lw2r[o];
        float4 res;
        float* rp = (float*)&res;
        #pragma unroll
        for (int px = 0; px < PIX; px++) {
            float d2g = fmaf(-2.f, acg[px], x2g[px] + w2gv);
            float d2r = fmaf(-2.f, acr[px], x2r[px] + w2rv);
            d2g = fmaxf(d2g, 1e-12f);
            d2r = fmaxf(d2r, 1e-12f);
            float d = __builtin_amdgcn_sqrtf(d2g) + __builtin_amdgcn_sqrtf(d2r);
            rp[px] = __expf(kneg * d * d);
        }
        *(float4*)(outp + (size_t)o * (OHW * OHW)) = res;
    }
}

extern "C" void kernel_launch(void* const* d_in, const int* in_sizes, int n_in,
                              void* d_out, int out_size, void* d_ws, size_t ws_size,
                              hipStream_t stream) {
    const float* gx   = (const float*)d_in[0];
    const float* rx   = (const float*)d_in[1];
    const float* gw   = (const float*)d_in[2];
    const float* rw   = (const float*)d_in[3];
    const float* stdp = (const float*)d_in[4];
    float* out = (float*)d_out;

    const int ngroups = BB * OHW * OWG;               // 46656 thread-groups of work
    dim3 grid((ngroups + 255) / 256, OO / OCHUNK, 1); // 183 x 8
    dim3 block(256, 1, 1);
    dist_rbf_kernel<<<grid, block, 0, stream>>>(gx, rx, gw, rw, stdp, out);
}

// Round 7
// 89.854 us; speedup vs baseline: 1.3051x; 1.0525x over previous
//
#include <hip/hip_runtime.h>
#include <math.h>

// Problem constants (from reference)
#define BB    16      // batch
#define HH    112     // H == W
#define OO    256     // output channels
#define KK    5       // kernel size
#define OHW   108     // output H == W (112 - 5 + 1)
#define PIX   4       // output pixels per thread (horizontally adjacent)
#define OWG   27      // 108 / 4 groups per output row
#define OCHUNK 32     // o-channels per block (grid.y = 256/32 = 8)
#define WREC  28      // padded LDS record: [0..24]=w, [25]=||w||^2, [26,27]=unused

// Pin a float into a VGPR (opaque identity asm) so the compiler cannot
// rematerialize/re-sink its producer into the o-loop.
#define KEEP(x) asm volatile("" : "+v"(x))

// Constant-index component access into a float4 array held in registers.
// k must be a compile-time constant (fully unrolled loops) so the ternary
// folds -- avoids pointer-aliasing the array (which risks scratch).
#define WCOMP(W, k) (((k) & 3) == 0 ? W[(k) >> 2].x : \
                     ((k) & 3) == 1 ? W[(k) >> 2].y : \
                     ((k) & 3) == 2 ? W[(k) >> 2].z : W[(k) >> 2].w)

// 25-tap correlation of a pinned 5x8 window against weight buffer WBUF
// (float4[7] in regs), accumulating PIX adjacent pixels.
#define CONV_PHASE(WIN, WBUF, ACC)                                        \
    do {                                                                  \
        _Pragma("unroll")                                                 \
        for (int r_ = 0; r_ < 5; r_++) {                                  \
            _Pragma("unroll")                                             \
            for (int c_ = 0; c_ < 5; c_++) {                              \
                const float wv_ = WCOMP(WBUF, r_ * 5 + c_);               \
                _Pragma("unroll")                                         \
                for (int px_ = 0; px_ < PIX; px_++)                       \
                    ACC[px_] = fmaf(WIN[r_][px_ + c_], wv_, ACC[px_]);    \
            }                                                             \
        }                                                                 \
    } while (0)

__global__ __attribute__((amdgpu_flat_work_group_size(256, 256),
                          amdgpu_waves_per_eu(1, 4)))
void dist_rbf_kernel(const float* __restrict__ gx, const float* __restrict__ rx,
                     const float* __restrict__ gw, const float* __restrict__ rw,
                     const float* __restrict__ stdp, float* __restrict__ out)
{
    // [0 .. OCHUNK*WREC) = gray records, [OCHUNK*WREC ..) = rgb records
    __shared__ __align__(16) float lw[2 * OCHUNK * WREC];

    const int tid   = threadIdx.x;
    const int obase = blockIdx.y * OCHUNK;

    // ---- stage weights into padded LDS records (elements 26,27 never read) ----
    for (int k = tid; k < OCHUNK * WREC; k += 256) {
        int o = k / WREC;
        int i = k - o * WREC;
        if (i < 25) {
            lw[k]                 = gw[(obase + o) * 25 + i];
            lw[OCHUNK * WREC + k] = rw[(obase + o) * 25 + i];
        }
    }
    // ||w||^2 into element 25 of each record (disjoint slots from above)
    if (tid < OCHUNK) {
        float s = 0.f;
        #pragma unroll
        for (int i = 0; i < 25; i++) { float v = gw[(obase + tid) * 25 + i]; s = fmaf(v, v, s); }
        lw[tid * WREC + 25] = s;
    } else if (tid < 2 * OCHUNK) {
        int o = tid - OCHUNK;
        float s = 0.f;
        #pragma unroll
        for (int i = 0; i < 25; i++) { float v = rw[(obase + o) * 25 + i]; s = fmaf(v, v, s); }
        lw[OCHUNK * WREC + o * WREC + 25] = s;
    }
    __syncthreads();

    const int g = blockIdx.x * 256 + tid;
    if (g >= BB * OHW * OWG) return;   // no barriers after this point

    const int b   = g / (OHW * OWG);
    const int rem = g - b * (OHW * OWG);
    const int oh  = rem / OWG;
    const int ow0 = (rem - oh * OWG) * PIX;

    const float s    = stdp[0];
    const float kneg = -1.f / (2.f * s * s);

    // ---- load 5x8 windows for both images into registers, pin them ----
    float wing[5][8], winr[5][8];
    const float* gbase = gx + ((b * HH) + oh) * HH + ow0;  // [B,1,112,112]
    const float* rbase = rx + ((b * HH) + oh) * HH + ow0;
    #pragma unroll
    for (int r = 0; r < 5; r++) {
        float4 a0 = *(const float4*)(gbase + r * HH);
        float4 a1 = *(const float4*)(gbase + r * HH + 4);
        wing[r][0] = a0.x; wing[r][1] = a0.y; wing[r][2] = a0.z; wing[r][3] = a0.w;
        wing[r][4] = a1.x; wing[r][5] = a1.y; wing[r][6] = a1.z; wing[r][7] = a1.w;
        float4 b0 = *(const float4*)(rbase + r * HH);
        float4 b1 = *(const float4*)(rbase + r * HH + 4);
        winr[r][0] = b0.x; winr[r][1] = b0.y; winr[r][2] = b0.z; winr[r][3] = b0.w;
        winr[r][4] = b1.x; winr[r][5] = b1.y; winr[r][6] = b1.z; winr[r][7] = b1.w;
    }
    #pragma unroll
    for (int r = 0; r < 5; r++)
        #pragma unroll
        for (int c = 0; c < 8; c++) { KEEP(wing[r][c]); KEEP(winr[r][c]); }

    // ---- per-pixel window sum-of-squares, pinned ----
    float x2g[PIX], x2r[PIX];
    #pragma unroll
    for (int px = 0; px < PIX; px++) {
        float sg = 0.f, sr = 0.f;
        #pragma unroll
        for (int r = 0; r < 5; r++)
            #pragma unroll
            for (int c = 0; c < 5; c++) {
                sg = fmaf(wing[r][px + c], wing[r][px + c], sg);
                sr = fmaf(winr[r][px + c], winr[r][px + c], sr);
            }
        x2g[px] = sg;
        x2r[px] = sr;
        KEEP(x2g[px]); KEEP(x2r[px]);
    }

    float* op = out + (((size_t)(b * OO + obase) * OHW) + oh) * OHW + ow0;

    const float4* lg4 = (const float4*)lw;                        // 7 float4 / record
    const float4* lr4 = (const float4*)(lw + OCHUNK * WREC);

    // ---- software-pipelined o-loop (unroll x2, ping-pong gray buffers) ----
    // Per sub-iter: issue rgb(o) ds_reads -> gray FMA burst -> issue gray(o+1)
    // ds_reads -> rgb FMA burst -> epilogue. Every ds_read batch has a ~200cy
    // FMA burst between issue and first use.
    float4 wA[7], wB[7];
    #pragma unroll
    for (int i = 0; i < 7; i++) wA[i] = lg4[i];   // gray(0)

#define SUB_ITER(WGBUF, WGNEXT, OIDX, ONEXT)                                  \
    do {                                                                      \
        float4 v_[7];                                                         \
        _Pragma("unroll")                                                     \
        for (int i = 0; i < 7; i++) v_[i] = lr4[(OIDX) * 7 + i];              \
        float acg[PIX] = {0.f, 0.f, 0.f, 0.f};                                \
        CONV_PHASE(wing, WGBUF, acg);                                         \
        _Pragma("unroll")                                                     \
        for (int i = 0; i < 7; i++) WGNEXT[i] = lg4[(ONEXT) * 7 + i];         \
        float acr[PIX] = {0.f, 0.f, 0.f, 0.f};                                \
        CONV_PHASE(winr, v_, acr);                                            \
        const float w2g = WCOMP(WGBUF, 25);                                   \
        const float w2r = WCOMP(v_, 25);                                      \
        float4 res;                                                           \
        float* rp = (float*)&res;                                             \
        _Pragma("unroll")                                                     \
        for (int px = 0; px < PIX; px++) {                                    \
            float d2g = fmaf(-2.f, acg[px], x2g[px] + w2g);                   \
            float d2r = fmaf(-2.f, acr[px], x2r[px] + w2r);                   \
            d2g = fmaxf(d2g, 1e-12f);                                         \
            d2r = fmaxf(d2r, 1e-12f);                                         \
            float d = __builtin_amdgcn_sqrtf(d2g) + __builtin_amdgcn_sqrtf(d2r); \
            rp[px] = __expf(kneg * d * d);                                    \
        }                                                                     \
        *(float4*)op = res;                                                   \
        op += (size_t)OHW * OHW;                                              \
    } while (0)

    for (int o = 0; o < OCHUNK; o += 2) {
        const int on1 = o + 1;
        const int on2 = (o + 2 < OCHUNK) ? o + 2 : 0;  // last prefetch harmless
        SUB_ITER(wA, wB, o,   on1);
        SUB_ITER(wB, wA, on1, on2);
    }
#undef SUB_ITER
}

extern "C" void kernel_launch(void* const* d_in, const int* in_sizes, int n_in,
                              void* d_out, int out_size, void* d_ws, size_t ws_size,
                              hipStream_t stream) {
    const float* gx   = (const float*)d_in[0];
    const float* rx   = (const float*)d_in[1];
    const float* gw   = (const float*)d_in[2];
    const float* rw   = (const float*)d_in[3];
    const float* stdp = (const float*)d_in[4];
    float* out = (float*)d_out;

    const int ngroups = BB * OHW * OWG;               // 46656 thread-groups of work
    dim3 grid((ngroups + 255) / 256, OO / OCHUNK, 1); // 183 x 8
    dim3 block(256, 1, 1);
    dist_rbf_kernel<<<grid, block, 0, stream>>>(gx, rx, gw, rw, stdp, out);
}

// Round 8
// 57.403 us; speedup vs baseline: 2.0430x; 1.5653x over previous
//
#include <hip/hip_runtime.h>
#include <math.h>

// Problem constants
#define BB    16                 // batch
#define HH    112                // input H == W
#define IMSZ  (HH*HH)            // 12544 floats per image plane
#define OO    256                // output channels
#define OHW   108                // output H == W
#define PLANE (OHW*OHW)          // 11664 pixels per (b,o) plane
#define MTOTAL (BB*PLANE)        // 186624 output pixels per o
#define MTILE 128                // pixels per block (8 M-frags, 2 per wave)
#define WRECB 144                // weight record bytes: hi[64] | lo[64] | pad[16]
#define WRECW 36                 // record size in u32 words

typedef __attribute__((ext_vector_type(8))) short short8;   // 8 bf16 = 4 VGPR
typedef __attribute__((ext_vector_type(4))) float f32x4;

// round-to-nearest-even float -> bf16 (bit trick; inputs finite)
__device__ __forceinline__ unsigned short f2bf(float x) {
    unsigned u = __builtin_bit_cast(unsigned, x);
    return (unsigned short)((u + 0x7fffu + ((u >> 16) & 1u)) >> 16);
}
__device__ __forceinline__ float bf2f(unsigned short h) {
    unsigned u = ((unsigned)h) << 16;
    return __builtin_bit_cast(float, u);
}

// GEMM formulation: xw[p,o] = sum_k win[p][k] * w[o][k], K=25 padded to 32.
// bf16 hi/lo split, 3 MFMAs (hh, hl, lh) per image -> ~2^-18 relative error.
// d2 = x2[p] + w2[o] - 2*xw  (x2, w2 exact fp32);  out = exp(-(dg+dr)^2/(2s^2)).
__global__ __launch_bounds__(256)
void dist_rbf_mfma(const float* __restrict__ gx, const float* __restrict__ rx,
                   const float* __restrict__ gw, const float* __restrict__ rw,
                   const float* __restrict__ stdp, float* __restrict__ out)
{
    __shared__ __align__(16) unsigned wrec[2 * OO * WRECW];  // gray | rgb records
    __shared__ float w2s[2 * OO];

    const int tid = threadIdx.x;

    // ---------------- stage weights: thread t <-> filter o = t ----------------
    #pragma unroll
    for (int img = 0; img < 2; img++) {
        const float* wsrc = img ? rw : gw;
        unsigned* rec = wrec + img * OO * WRECW + tid * WRECW;
        float v[32]; unsigned short h[32];
        float s = 0.f;
        #pragma unroll
        for (int i = 0; i < 32; i++) {
            float x = (i < 25) ? wsrc[tid * 25 + i] : 0.f;
            v[i] = x; s = fmaf(x, x, s); h[i] = f2bf(x);
        }
        w2s[img * OO + tid] = s;
        #pragma unroll
        for (int wd = 0; wd < 16; wd++) {
            rec[wd] = (unsigned)h[2*wd] | ((unsigned)h[2*wd+1] << 16);
            unsigned short l0 = f2bf(v[2*wd]   - bf2f(h[2*wd]));
            unsigned short l1 = f2bf(v[2*wd+1] - bf2f(h[2*wd+1]));
            rec[16 + wd] = (unsigned)l0 | ((unsigned)l1 << 16);
        }
    }
    __syncthreads();

    const int lid  = tid & 63;
    const int wid  = tid >> 6;
    const int mcol = lid & 15;     // A: pixel row; B: o col; C: col
    const int kgrp = lid >> 4;     // k-group: k in [kgrp*8, kgrp*8+8)
    const int k0   = kgrp * 8;

    const float sd   = stdp[0];
    const float kneg = -1.f / (2.f * sd * sd);

    const int pbase = blockIdx.x * MTILE;

    // ---------------- build A fragments + x2 in registers ----------------
    short8 ah[2][2], al[2][2];     // [mf][img]
    float  x2v[2][2][4];           // [mf][img][r] : x2 of pixel row kgrp*4+r

    #pragma unroll
    for (int mf = 0; mf < 2; mf++) {
        const int p  = pbase + (wid * 2 + mf) * 16 + mcol;  // this lane's A row
        const int b  = p / PLANE;
        const int pp = p - b * PLANE;
        const int oh = pp / OHW;
        const int ow = pp - oh * OHW;
        const size_t ibase = (size_t)b * IMSZ + oh * HH + ow;
        #pragma unroll
        for (int img = 0; img < 2; img++) {
            const float* src = (img == 0 ? gx : rx) + ibase;
            float xs[8];
            float part = 0.f;
            #pragma unroll
            for (int j = 0; j < 8; j++) {
                int k = k0 + j;
                int r = k / 5, c = k - r * 5;
                float x = (k < 25) ? src[r * HH + c] : 0.f;
                xs[j] = x; part = fmaf(x, x, part);
            }
            // reduce partial x2 across the 4 k-groups of this pixel
            part += __shfl_xor(part, 16);
            part += __shfl_xor(part, 32);
            // fetch x2 for the epilogue's C rows (pixels kgrp*4 + r)
            #pragma unroll
            for (int r = 0; r < 4; r++)
                x2v[mf][img][r] = __shfl(part, kgrp * 4 + r);
            // bf16 hi/lo split
            short8 hi, lo;
            #pragma unroll
            for (int j = 0; j < 8; j++) {
                unsigned short hh = f2bf(xs[j]);
                hi[j] = (short)hh;
                lo[j] = (short)f2bf(xs[j] - bf2f(hh));
            }
            ah[mf][img] = hi; al[mf][img] = lo;
        }
    }

    // ---------------- main loop over 16 o-tiles ----------------
    const char* wrecB = (const char*)wrec;
    #pragma unroll 2
    for (int ot = 0; ot < 16; ot++) {
        const int o = ot * 16 + mcol;
        const char* recg = wrecB + (size_t)o * WRECB + kgrp * 16;
        const char* recr = recg + (size_t)OO * WRECB;
        short8 bhg = *(const short8*)recg;
        short8 blg = *(const short8*)(recg + 64);
        short8 bhr = *(const short8*)recr;
        short8 blr = *(const short8*)(recr + 64);
        const float w2g = w2s[o];
        const float w2r = w2s[OO + o];

        #pragma unroll
        for (int mf = 0; mf < 2; mf++) {
            f32x4 cg = {0.f, 0.f, 0.f, 0.f};
            f32x4 cr = {0.f, 0.f, 0.f, 0.f};
            cg = __builtin_amdgcn_mfma_f32_16x16x32_bf16(ah[mf][0], bhg, cg, 0, 0, 0);
            cg = __builtin_amdgcn_mfma_f32_16x16x32_bf16(ah[mf][0], blg, cg, 0, 0, 0);
            cg = __builtin_amdgcn_mfma_f32_16x16x32_bf16(al[mf][0], bhg, cg, 0, 0, 0);
            cr = __builtin_amdgcn_mfma_f32_16x16x32_bf16(ah[mf][1], bhr, cr, 0, 0, 0);
            cr = __builtin_amdgcn_mfma_f32_16x16x32_bf16(ah[mf][1], blr, cr, 0, 0, 0);
            cr = __builtin_amdgcn_mfma_f32_16x16x32_bf16(al[mf][1], bhr, cr, 0, 0, 0);

            // epilogue: 4 outputs = C rows kgrp*4+r (pixels), col o
            f32x4 res;
            #pragma unroll
            for (int r = 0; r < 4; r++) {
                float d2g = fmaf(-2.f, cg[r], x2v[mf][0][r] + w2g);
                float d2r = fmaf(-2.f, cr[r], x2v[mf][1][r] + w2r);
                d2g = fmaxf(d2g, 1e-12f);
                d2r = fmaxf(d2r, 1e-12f);
                float d = __builtin_amdgcn_sqrtf(d2g) + __builtin_amdgcn_sqrtf(d2r);
                res[r] = __expf(kneg * d * d);
            }
            const int prow0 = pbase + (wid * 2 + mf) * 16 + kgrp * 4;
            const int b0  = prow0 / PLANE;
            const int pp0 = prow0 - b0 * PLANE;
            if (pp0 <= PLANE - 4) {
                // 4 consecutive pixels, same (b,o) plane -> one dwordx4
                *(f32x4*)(out + ((size_t)(b0 * OO + o)) * PLANE + pp0) = res;
            } else {
                #pragma unroll
                for (int r = 0; r < 4; r++) {
                    int pr  = prow0 + r;
                    int br  = pr / PLANE, ppr = pr - br * PLANE;
                    out[((size_t)(br * OO + o)) * PLANE + ppr] = res[r];
                }
            }
        }
    }
}

extern "C" void kernel_launch(void* const* d_in, const int* in_sizes, int n_in,
                              void* d_out, int out_size, void* d_ws, size_t ws_size,
                              hipStream_t stream) {
    const float* gx   = (const float*)d_in[0];
    const float* rx   = (const float*)d_in[1];
    const float* gw   = (const float*)d_in[2];
    const float* rw   = (const float*)d_in[3];
    const float* stdp = (const float*)d_in[4];
    float* out = (float*)d_out;

    dim3 grid(MTOTAL / MTILE, 1, 1);   // 1458 blocks, exact
    dim3 block(256, 1, 1);
    dist_rbf_mfma<<<grid, block, 0, stream>>>(gx, rx, gw, rw, stdp, out);
}

// Round 11
// 50.852 us; speedup vs baseline: 2.3062x; 1.1288x over previous
//
#include <hip/hip_runtime.h>
#include <math.h>

// Problem constants
#define BB    16                 // batch
#define HH    112                // input H == W
#define IMSZ  (HH*HH)            // 12544 floats per image plane
#define OO    256                // output channels
#define OHW   108                // output H == W
#define PLANE (OHW*OHW)          // 11664 pixels per (b,o) plane
#define MTOTAL (BB*PLANE)        // 186624 output pixels per o
#define MTILE 256                // pixels per block (16 M-frags, 2 per wave)
#define WRECB 144                // weight record bytes: hi[64] | lo[64] | pad[16]
#define WRECW 36                 // record size in u32 words

typedef __attribute__((ext_vector_type(8))) short short8;   // 8 bf16 = 4 VGPR
typedef __attribute__((ext_vector_type(4))) float f32x4;

// round-to-nearest-even float -> bf16 (bit trick; inputs finite)
__device__ __forceinline__ unsigned short f2bf(float x) {
    unsigned u = __builtin_bit_cast(unsigned, x);
    return (unsigned short)((u + 0x7fffu + ((u >> 16) & 1u)) >> 16);
}
__device__ __forceinline__ float bf2f(unsigned short h) {
    unsigned u = ((unsigned)h) << 16;
    return __builtin_bit_cast(float, u);
}

// GEMM formulation: xw[p,o] = sum_k win[p][k] * w[o][k], K=25 padded to 32.
// bf16 hi/lo split, 3 MFMAs (hh, hl, lh) per image -> ~2^-18 relative error.
// d2 = x2[p] + w2[o] - 2*xw  (x2, w2 exact fp32).
// (sqrt(a)+sqrt(b))^2 = a + b + 2*sqrt(a*b)  -> 1 sqrt + 1 exp per output.
__global__ __launch_bounds__(512)
void dist_rbf_mfma(const float* __restrict__ gx, const float* __restrict__ rx,
                   const float* __restrict__ gw, const float* __restrict__ rw,
                   const float* __restrict__ stdp, float* __restrict__ out)
{
    __shared__ __align__(16) unsigned wrec[2 * OO * WRECW];  // gray | rgb records
    __shared__ float w2s[2 * OO];

    const int tid = threadIdx.x;

    // ---- stage weights: thread t handles image t>>8, filter t&255 ----
    {
        const int img = tid >> 8;
        const int o   = tid & 255;
        const float* wsrc = img ? rw : gw;
        unsigned* rec = wrec + img * OO * WRECW + o * WRECW;
        float v[32]; unsigned short h[32];
        float s = 0.f;
        #pragma unroll
        for (int i = 0; i < 32; i++) {
            float x = (i < 25) ? wsrc[o * 25 + i] : 0.f;
            v[i] = x; s = fmaf(x, x, s); h[i] = f2bf(x);
        }
        w2s[img * OO + o] = s;
        #pragma unroll
        for (int wd = 0; wd < 16; wd++) {
            rec[wd] = (unsigned)h[2*wd] | ((unsigned)h[2*wd+1] << 16);
            unsigned short l0 = f2bf(v[2*wd]   - bf2f(h[2*wd]));
            unsigned short l1 = f2bf(v[2*wd+1] - bf2f(h[2*wd+1]));
            rec[16 + wd] = (unsigned)l0 | ((unsigned)l1 << 16);
        }
    }
    __syncthreads();

    const int lid  = tid & 63;
    const int wid  = tid >> 6;     // 8 waves
    const int mcol = lid & 15;     // A: pixel row; B: o col; C: col
    const int kgrp = lid >> 4;     // k-group: k in [kgrp*8, kgrp*8+8)
    const int k0   = kgrp * 8;

    const float sd   = stdp[0];
    const float kneg = -1.f / (2.f * sd * sd);

    const int pbase = blockIdx.x * MTILE;

    // ---------------- build A fragments + x2 in registers ----------------
    short8 ah[2][2], al[2][2];     // [mf][img]
    float  x2v[2][2][4];           // [mf][img][r] : x2 of pixel row kgrp*4+r

    #pragma unroll
    for (int mf = 0; mf < 2; mf++) {
        const int p  = pbase + (wid * 2 + mf) * 16 + mcol;  // this lane's A row
        const int b  = p / PLANE;
        const int pp = p - b * PLANE;
        const int oh = pp / OHW;
        const int ow = pp - oh * OHW;
        const size_t ibase = (size_t)b * IMSZ + oh * HH + ow;
        #pragma unroll
        for (int img = 0; img < 2; img++) {
            const float* src = (img == 0 ? gx : rx) + ibase;
            float xs[8];
            float part = 0.f;
            #pragma unroll
            for (int j = 0; j < 8; j++) {
                int k = k0 + j;
                int r = k / 5, c = k - r * 5;
                float x = (k < 25) ? src[r * HH + c] : 0.f;
                xs[j] = x; part = fmaf(x, x, part);
            }
            // reduce partial x2 across the 4 k-groups of this pixel
            part += __shfl_xor(part, 16);
            part += __shfl_xor(part, 32);
            // fetch x2 for the epilogue's C rows (pixels kgrp*4 + r)
            #pragma unroll
            for (int r = 0; r < 4; r++)
                x2v[mf][img][r] = __shfl(part, kgrp * 4 + r);
            // bf16 hi/lo split
            short8 hi, lo;
            #pragma unroll
            for (int j = 0; j < 8; j++) {
                unsigned short hh = f2bf(xs[j]);
                hi[j] = (short)hh;
                lo[j] = (short)f2bf(xs[j] - bf2f(hh));
            }
            ah[mf][img] = hi; al[mf][img] = lo;
        }
    }

    // ---------------- main loop over 16 o-tiles ----------------
    const char* wrecB = (const char*)wrec;
    #pragma unroll 2
    for (int ot = 0; ot < 16; ot++) {
        const int o = ot * 16 + mcol;
        const char* recg = wrecB + (size_t)o * WRECB + kgrp * 16;
        const char* recr = recg + (size_t)OO * WRECB;
        short8 bhg = *(const short8*)recg;
        short8 blg = *(const short8*)(recg + 64);
        short8 bhr = *(const short8*)recr;
        short8 blr = *(const short8*)(recr + 64);
        const float w2g = w2s[o];
        const float w2r = w2s[OO + o];

        #pragma unroll
        for (int mf = 0; mf < 2; mf++) {
            f32x4 cg = {0.f, 0.f, 0.f, 0.f};
            f32x4 cr = {0.f, 0.f, 0.f, 0.f};
            cg = __builtin_amdgcn_mfma_f32_16x16x32_bf16(ah[mf][0], bhg, cg, 0, 0, 0);
            cg = __builtin_amdgcn_mfma_f32_16x16x32_bf16(ah[mf][0], blg, cg, 0, 0, 0);
            cg = __builtin_amdgcn_mfma_f32_16x16x32_bf16(al[mf][0], bhg, cg, 0, 0, 0);
            cr = __builtin_amdgcn_mfma_f32_16x16x32_bf16(ah[mf][1], bhr, cr, 0, 0, 0);
            cr = __builtin_amdgcn_mfma_f32_16x16x32_bf16(ah[mf][1], blr, cr, 0, 0, 0);
            cr = __builtin_amdgcn_mfma_f32_16x16x32_bf16(al[mf][1], bhr, cr, 0, 0, 0);

            // epilogue: 4 outputs = C rows kgrp*4+r (pixels), col o
            f32x4 res;
            #pragma unroll
            for (int r = 0; r < 4; r++) {
                float d2g = fmaf(-2.f, cg[r], x2v[mf][0][r] + w2g);
                float d2r = fmaf(-2.f, cr[r], x2v[mf][1][r] + w2r);
                d2g = fmaxf(d2g, 1e-12f);
                d2r = fmaxf(d2r, 1e-12f);
                // (sqrt(d2g)+sqrt(d2r))^2 = d2g + d2r + 2*sqrt(d2g*d2r)
                float d2 = fmaf(2.f, __builtin_amdgcn_sqrtf(d2g * d2r), d2g + d2r);
                res[r] = __expf(kneg * d2);
            }
            // PLANE and prow0 are both multiples of 4 -> a 4-px group never
            // straddles a plane boundary; always one dwordx4.
            const int prow0 = pbase + (wid * 2 + mf) * 16 + kgrp * 4;
            const int b0  = prow0 / PLANE;
            const int pp0 = prow0 - b0 * PLANE;
            *(f32x4*)(out + ((size_t)(b0 * OO + o)) * PLANE + pp0) = res;
        }
    }
}

extern "C" void kernel_launch(void* const* d_in, const int* in_sizes, int n_in,
                              void* d_out, int out_size, void* d_ws, size_t ws_size,
                              hipStream_t stream) {
    const float* gx   = (const float*)d_in[0];
    const float* rx   = (const float*)d_in[1];
    const float* gw   = (const float*)d_in[2];
    const float* rw   = (const float*)d_in[3];
    const float* stdp = (const float*)d_in[4];
    float* out = (float*)d_out;

    dim3 grid(MTOTAL / MTILE, 1, 1);   // 729 blocks, exact
    dim3 block(512, 1, 1);
    dist_rbf_mfma<<<grid, block, 0, stream>>>(gx, rx, gw, rw, stdp, out);
}

// Round 12
// 50.290 us; speedup vs baseline: 2.3319x; 1.0112x over previous
//
#include <hip/hip_runtime.h>
#include <math.h>

// Problem constants
#define BB    16                 // batch
#define HH    112                // input H == W
#define IMSZ  (HH*HH)            // 12544 floats per image plane
#define OO    256                // output channels
#define OHW   108                // output H == W
#define PLANE (OHW*OHW)          // 11664 pixels per (b,o) plane
#define MTOTAL (BB*PLANE)        // 186624 output pixels per o
#define MTILE 256                // pixels per block (16 M-frags, 2 per wave)
#define WRECB 144                // weight record bytes: hi[64] | lo[64] | pad[16]
#define WRECW 36                 // record size in u32 words
#define NXCD  8

typedef __attribute__((ext_vector_type(8))) short short8;   // 8 bf16 = 4 VGPR
typedef __attribute__((ext_vector_type(4))) float f32x4;

// round-to-nearest-even float -> bf16 (bit trick; inputs finite)
__device__ __forceinline__ unsigned short f2bf(float x) {
    unsigned u = __builtin_bit_cast(unsigned, x);
    return (unsigned short)((u + 0x7fffu + ((u >> 16) & 1u)) >> 16);
}
__device__ __forceinline__ float bf2f(unsigned short h) {
    unsigned u = ((unsigned)h) << 16;
    return __builtin_bit_cast(float, u);
}

// GEMM formulation: xw[p,o] = sum_k win[p][k] * w[o][k], K=25 padded to 32.
// bf16 hi/lo split, 3 MFMAs (hh, hl, lh) per image -> ~2^-18 relative error.
// d2 = x2[p] + w2[o] - 2*xw  (x2, w2 exact fp32).
// (sqrt(a)+sqrt(b))^2 = a + b + 2*sqrt(a*b)  -> 1 sqrt + 1 exp per output.
__global__ __launch_bounds__(512)
void dist_rbf_mfma(const float* __restrict__ gx, const float* __restrict__ rx,
                   const float* __restrict__ gw, const float* __restrict__ rw,
                   const float* __restrict__ stdp, float* __restrict__ out)
{
    __shared__ __align__(16) unsigned wrec[2 * OO * WRECW];  // gray | rgb records
    __shared__ float w2s[2 * OO];

    const int tid = threadIdx.x;

    // ---- bijective XCD swizzle (m204): consecutive logical pixel-tiles on
    // the same XCD so adjacent per-plane write runs merge in one L2 ----
    const int nwg = gridDim.x;                 // 729 (not divisible by 8)
    const int hw  = blockIdx.x;
    const int xcd = hw % NXCD, idx = hw / NXCD;
    const int q = nwg / NXCD, r = nwg % NXCD;
    const int lb = (xcd < r ? xcd * (q + 1) : r * (q + 1) + (xcd - r) * q) + idx;

    // ---- stage weights: thread t handles image t>>8, filter t&255 ----
    {
        const int img = tid >> 8;
        const int o   = tid & 255;
        const float* wsrc = img ? rw : gw;
        unsigned* rec = wrec + img * OO * WRECW + o * WRECW;
        float v[32]; unsigned short h[32];
        float s = 0.f;
        #pragma unroll
        for (int i = 0; i < 32; i++) {
            float x = (i < 25) ? wsrc[o * 25 + i] : 0.f;
            v[i] = x; s = fmaf(x, x, s); h[i] = f2bf(x);
        }
        w2s[img * OO + o] = s;
        #pragma unroll
        for (int wd = 0; wd < 16; wd++) {
            rec[wd] = (unsigned)h[2*wd] | ((unsigned)h[2*wd+1] << 16);
            unsigned short l0 = f2bf(v[2*wd]   - bf2f(h[2*wd]));
            unsigned short l1 = f2bf(v[2*wd+1] - bf2f(h[2*wd+1]));
            rec[16 + wd] = (unsigned)l0 | ((unsigned)l1 << 16);
        }
    }
    __syncthreads();

    const int lid  = tid & 63;
    const int wid  = tid >> 6;     // 8 waves
    const int mcol = lid & 15;     // A: pixel row; B: o col; C: col
    const int kgrp = lid >> 4;     // k-group: k in [kgrp*8, kgrp*8+8)
    const int k0   = kgrp * 8;

    const float sd   = stdp[0];
    const float kneg = -1.f / (2.f * sd * sd);

    const int pbase = lb * MTILE;

    // ---------------- build A fragments + x2 in registers ----------------
    short8 ah[2][2], al[2][2];     // [mf][img]
    float  x2v[2][2][4];           // [mf][img][r] : x2 of pixel row kgrp*4+r

    #pragma unroll
    for (int mf = 0; mf < 2; mf++) {
        const int p  = pbase + (wid * 2 + mf) * 16 + mcol;  // this lane's A row
        const int b  = p / PLANE;
        const int pp = p - b * PLANE;
        const int oh = pp / OHW;
        const int ow = pp - oh * OHW;
        const size_t ibase = (size_t)b * IMSZ + oh * HH + ow;
        #pragma unroll
        for (int img = 0; img < 2; img++) {
            const float* src = (img == 0 ? gx : rx) + ibase;
            float xs[8];
            float part = 0.f;
            #pragma unroll
            for (int j = 0; j < 8; j++) {
                int k = k0 + j;
                int r2 = k / 5, c2 = k - r2 * 5;
                float x = (k < 25) ? src[r2 * HH + c2] : 0.f;
                xs[j] = x; part = fmaf(x, x, part);
            }
            // reduce partial x2 across the 4 k-groups of this pixel
            part += __shfl_xor(part, 16);
            part += __shfl_xor(part, 32);
            // fetch x2 for the epilogue's C rows (pixels kgrp*4 + r)
            #pragma unroll
            for (int rr = 0; rr < 4; rr++)
                x2v[mf][img][rr] = __shfl(part, kgrp * 4 + rr);
            // bf16 hi/lo split
            short8 hi, lo;
            #pragma unroll
            for (int j = 0; j < 8; j++) {
                unsigned short hh = f2bf(xs[j]);
                hi[j] = (short)hh;
                lo[j] = (short)f2bf(xs[j] - bf2f(hh));
            }
            ah[mf][img] = hi; al[mf][img] = lo;
        }
    }

    // ---------------- main loop over 16 o-tiles ----------------
    const char* wrecB = (const char*)wrec;
    #pragma unroll 2
    for (int ot = 0; ot < 16; ot++) {
        const int o = ot * 16 + mcol;
        const char* recg = wrecB + (size_t)o * WRECB + kgrp * 16;
        const char* recr = recg + (size_t)OO * WRECB;
        short8 bhg = *(const short8*)recg;
        short8 blg = *(const short8*)(recg + 64);
        short8 bhr = *(const short8*)recr;
        short8 blr = *(const short8*)(recr + 64);
        const float w2g = w2s[o];
        const float w2r = w2s[OO + o];

        #pragma unroll
        for (int mf = 0; mf < 2; mf++) {
            f32x4 cg = {0.f, 0.f, 0.f, 0.f};
            f32x4 cr = {0.f, 0.f, 0.f, 0.f};
            cg = __builtin_amdgcn_mfma_f32_16x16x32_bf16(ah[mf][0], bhg, cg, 0, 0, 0);
            cg = __builtin_amdgcn_mfma_f32_16x16x32_bf16(ah[mf][0], blg, cg, 0, 0, 0);
            cg = __builtin_amdgcn_mfma_f32_16x16x32_bf16(al[mf][0], bhg, cg, 0, 0, 0);
            cr = __builtin_amdgcn_mfma_f32_16x16x32_bf16(ah[mf][1], bhr, cr, 0, 0, 0);
            cr = __builtin_amdgcn_mfma_f32_16x16x32_bf16(ah[mf][1], blr, cr, 0, 0, 0);
            cr = __builtin_amdgcn_mfma_f32_16x16x32_bf16(al[mf][1], bhr, cr, 0, 0, 0);

            // epilogue: 4 outputs = C rows kgrp*4+r (pixels), col o
            f32x4 res;
            #pragma unroll
            for (int rr = 0; rr < 4; rr++) {
                float d2g = fmaf(-2.f, cg[rr], x2v[mf][0][rr] + w2g);
                float d2r = fmaf(-2.f, cr[rr], x2v[mf][1][rr] + w2r);
                d2g = fmaxf(d2g, 1e-12f);
                d2r = fmaxf(d2r, 1e-12f);
                // (sqrt(d2g)+sqrt(d2r))^2 = d2g + d2r + 2*sqrt(d2g*d2r)
                float d2 = fmaf(2.f, __builtin_amdgcn_sqrtf(d2g * d2r), d2g + d2r);
                res[rr] = __expf(kneg * d2);
            }
            // PLANE and prow0 are both multiples of 4 -> a 4-px group never
            // straddles a plane boundary; always one dwordx4.
            const int prow0 = pbase + (wid * 2 + mf) * 16 + kgrp * 4;
            const int b0  = prow0 / PLANE;
            const int pp0 = prow0 - b0 * PLANE;
            *(f32x4*)(out + ((size_t)(b0 * OO + o)) * PLANE + pp0) = res;
        }
    }
}

extern "C" void kernel_launch(void* const* d_in, const int* in_sizes, int n_in,
                              void* d_out, int out_size, void* d_ws, size_t ws_size,
                              hipStream_t stream) {
    const float* gx   = (const float*)d_in[0];
    const float* rx   = (const float*)d_in[1];
    const float* gw   = (const float*)d_in[2];
    const float* rw   = (const float*)d_in[3];
    const float* stdp = (const float*)d_in[4];
    float* out = (float*)d_out;

    dim3 grid(MTOTAL / MTILE, 1, 1);   // 729 blocks, exact
    dim3 block(512, 1, 1);
    dist_rbf_mfma<<<grid, block, 0, stream>>>(gx, rx, gw, rw, stdp, out);
}